// Round 1
// baseline (59776.385 us; speedup 1.0000x reference)
//
#include <hip/hip_runtime.h>
#include <stdint.h>

#define BB 32      // batch
#define TT 128     // seq len
#define HH 1024    // hidden
#define VV 32000   // vocab
#define HSQ (HH*HH)

typedef __attribute__((ext_vector_type(8))) short short8;
typedef __attribute__((ext_vector_type(4))) float floatx4;

__device__ __forceinline__ unsigned short f2bf(float f) {
  union { float f; uint32_t u; } v; v.f = f;
  uint32_t u = v.u;
  uint32_t r = (u + 0x7fffu + ((u >> 16) & 1u)) >> 16;  // RNE
  return (unsigned short)r;
}

__device__ __forceinline__ float sigm2(float x) {  // 2*sigmoid(x)
  return 2.f / (1.f + __expf(-x));
}

// ---------------------------------------------------------------------------
// Embedding gather: xs[t][b][:] = emb[seq[b][t]][:]
// grid 4096 x 256, one float4 per thread
__global__ __launch_bounds__(256) void gather_kernel(
    const int* __restrict__ seq, const float* __restrict__ emb,
    float* __restrict__ xs)
{
  int g = blockIdx.x * 256 + threadIdx.x;   // [0, B*T*H/4)
  int hq = g & 255;                         // H/4 = 256
  int bt = g >> 8;
  int b = bt >> 7;                          // /T
  int t = bt & 127;
  int tok = seq[b * TT + t];
  ((float4*)xs)[((size_t)t * BB + b) * 256 + hq] =
      ((const float4*)emb)[(size_t)tok * 256 + hq];
}

// fp32 -> bf16 conversion (for emb weights used by the big GEMM)
__global__ __launch_bounds__(256) void cvt_bf16_kernel(
    const float* __restrict__ in, unsigned short* __restrict__ out, int n4)
{
  int g = blockIdx.x * 256 + threadIdx.x;
  if (g < n4) {
    float4 v = ((const float4*)in)[g];
    ushort4 o;
    o.x = f2bf(v.x); o.y = f2bf(v.y); o.z = f2bf(v.z); o.w = f2bf(v.w);
    ((ushort4*)out)[g] = o;
  }
}

// ---------------------------------------------------------------------------
// One mogrify stage: dst[b,j] = 2*sigmoid(dot(vec[b,:], W[j,:]) + bias[j]) * src[b,j]
// grid 256 x 128 threads, one output per thread. b = low 5 bits so weight-row
// reads are broadcast within a wave; vec is L2/L1-hot (128 KB).
__global__ __launch_bounds__(128) void mog_kernel(
    const float* __restrict__ vec, const float* __restrict__ W,
    const float* __restrict__ bias, const float* src, float* dst)
{
  int g = blockIdx.x * 128 + threadIdx.x;   // [0, 32768)
  int b = g & 31;
  int j = g >> 5;
  const float4* vp = (const float4*)(vec + (size_t)b * HH);
  const float4* wp = (const float4*)(W + (size_t)j * HH);
  float a0 = 0.f, a1 = 0.f, a2 = 0.f, a3 = 0.f;
  #pragma unroll 8
  for (int k = 0; k < HH / 4; ++k) {
    float4 v = vp[k], w = wp[k];
    a0 += v.x * w.x; a1 += v.y * w.y; a2 += v.z * w.z; a3 += v.w * w.w;
  }
  float s = sigm2((a0 + a1) + (a2 + a3) + bias[j]);
  dst[(size_t)b * HH + j] = s * src[(size_t)b * HH + j];
}

// ---------------------------------------------------------------------------
// Fused LSTM cell: gates = X@wih^T + Hv@whh^T + bih + bhh; i,f,g,o split;
// c = sig(f)*c + sig(i)*tanh(g); h = sig(o)*tanh(c).
// grid 256 x 256. Thread (b, jl, kh): partial 4-gate dot over K-half, LDS reduce.
__global__ __launch_bounds__(256) void lstm_kernel(
    const float* __restrict__ X, const float* __restrict__ Hv,
    float* c,
    const float* __restrict__ wih, const float* __restrict__ whh,
    const float* __restrict__ bih, const float* __restrict__ bhh,
    float* hout, float* hid32, unsigned short* hidb, int t)
{
  int tid = threadIdx.x;
  int low = tid & 127;
  int b = low & 31;
  int jl = low >> 5;            // 0..3
  int kh = tid >> 7;            // 0..1 : K-half
  int j = blockIdx.x * 4 + jl;  // 0..1023

  const float4* xp = (const float4*)(X + (size_t)b * HH) + kh * 128;
  const float4* hp = (const float4*)(Hv + (size_t)b * HH) + kh * 128;
  const float4* wi0 = (const float4*)(wih + (size_t)(0 * HH + j) * HH) + kh * 128;
  const float4* wi1 = (const float4*)(wih + (size_t)(1 * HH + j) * HH) + kh * 128;
  const float4* wi2 = (const float4*)(wih + (size_t)(2 * HH + j) * HH) + kh * 128;
  const float4* wi3 = (const float4*)(wih + (size_t)(3 * HH + j) * HH) + kh * 128;
  const float4* wh0 = (const float4*)(whh + (size_t)(0 * HH + j) * HH) + kh * 128;
  const float4* wh1 = (const float4*)(whh + (size_t)(1 * HH + j) * HH) + kh * 128;
  const float4* wh2 = (const float4*)(whh + (size_t)(2 * HH + j) * HH) + kh * 128;
  const float4* wh3 = (const float4*)(whh + (size_t)(3 * HH + j) * HH) + kh * 128;

  float4 ai = {0,0,0,0}, af = {0,0,0,0}, ag = {0,0,0,0}, ao = {0,0,0,0};
  #pragma unroll 2
  for (int k = 0; k < 128; ++k) {
    float4 x4 = xp[k], h4 = hp[k];
    float4 w;
    w = wi0[k]; ai.x += x4.x*w.x; ai.y += x4.y*w.y; ai.z += x4.z*w.z; ai.w += x4.w*w.w;
    w = wh0[k]; ai.x += h4.x*w.x; ai.y += h4.y*w.y; ai.z += h4.z*w.z; ai.w += h4.w*w.w;
    w = wi1[k]; af.x += x4.x*w.x; af.y += x4.y*w.y; af.z += x4.z*w.z; af.w += x4.w*w.w;
    w = wh1[k]; af.x += h4.x*w.x; af.y += h4.y*w.y; af.z += h4.z*w.z; af.w += h4.w*w.w;
    w = wi2[k]; ag.x += x4.x*w.x; ag.y += x4.y*w.y; ag.z += x4.z*w.z; ag.w += x4.w*w.w;
    w = wh2[k]; ag.x += h4.x*w.x; ag.y += h4.y*w.y; ag.z += h4.z*w.z; ag.w += h4.w*w.w;
    w = wi3[k]; ao.x += x4.x*w.x; ao.y += x4.y*w.y; ao.z += x4.z*w.z; ao.w += x4.w*w.w;
    w = wh3[k]; ao.x += h4.x*w.x; ao.y += h4.y*w.y; ao.z += h4.z*w.z; ao.w += h4.w*w.w;
  }

  __shared__ float4 redi[128], redf[128], redg[128], redo[128];
  if (kh) { redi[low] = ai; redf[low] = af; redg[low] = ag; redo[low] = ao; }
  __syncthreads();
  if (!kh) {
    float4 r;
    r = redi[low]; ai.x += r.x; ai.y += r.y; ai.z += r.z; ai.w += r.w;
    r = redf[low]; af.x += r.x; af.y += r.y; af.z += r.z; af.w += r.w;
    r = redg[low]; ag.x += r.x; ag.y += r.y; ag.z += r.z; ag.w += r.w;
    r = redo[low]; ao.x += r.x; ao.y += r.y; ao.z += r.z; ao.w += r.w;
    float gi = (ai.x + ai.y) + (ai.z + ai.w) + bih[j]        + bhh[j];
    float gf = (af.x + af.y) + (af.z + af.w) + bih[HH + j]   + bhh[HH + j];
    float gg = (ag.x + ag.y) + (ag.z + ag.w) + bih[2*HH + j] + bhh[2*HH + j];
    float go = (ao.x + ao.y) + (ao.z + ao.w) + bih[3*HH + j] + bhh[3*HH + j];
    float ig = 0.5f * sigm2(gi);
    float fg = 0.5f * sigm2(gf);
    float og = 0.5f * sigm2(go);
    float gt = tanhf(gg);
    size_t idx = (size_t)b * HH + j;
    float cv = fg * c[idx] + ig * gt;
    c[idx] = cv;
    float hv = og * tanhf(cv);
    hout[idx] = hv;
    if (hid32) {
      size_t oidx = ((size_t)b * TT + t) * HH + j;
      hid32[oidx] = hv;
      hidb[oidx] = f2bf(hv);
    }
  }
}

// ---------------------------------------------------------------------------
// Final tied-embedding projection: out[n, v] = sum_k hid[n,k]*emb[v,k] + bias[v]
// bf16 MFMA 16x16x32, BM=BN=128, BK=32, 256 threads (4 waves, 64x64 each).
#define GBM 128
#define GBN 128
#define GBK 32
#define LDA 40   // padded LDS row stride in bf16 elems (32 + 8)

__global__ __launch_bounds__(256) void gemm_kernel(
    const unsigned short* __restrict__ A,   // [4096, 1024] bf16 row-major
    const unsigned short* __restrict__ Bm,  // [32000, 1024] bf16 row-major
    const float* __restrict__ bias,         // [32000]
    float* __restrict__ out)                // [4096, 32000] fp32
{
  __shared__ __align__(16) short As[GBM * LDA];
  __shared__ __align__(16) short Bs[GBN * LDA];
  int tid = threadIdx.x;
  int bn = blockIdx.x * GBN;
  int bm = blockIdx.y * GBM;
  int lane = tid & 63;
  int wave = tid >> 6;
  int wm = (wave & 1) * 64;
  int wn = (wave >> 1) * 64;
  int lrow = lane & 15;
  int quad = lane >> 4;

  floatx4 acc[4][4];
  #pragma unroll
  for (int i = 0; i < 4; ++i)
    #pragma unroll
    for (int jj = 0; jj < 4; ++jj) acc[i][jj] = (floatx4){0.f, 0.f, 0.f, 0.f};

  // staging: 128x32 bf16 tile = 512 16B-chunks; 2 chunks/thread
  int c0 = tid, c1 = tid + 256;
  int r0 = c0 >> 2, q0 = c0 & 3;
  int r1 = c1 >> 2, q1 = c1 & 3;

  for (int k0 = 0; k0 < 1024; k0 += GBK) {
    __syncthreads();
    uint4 va0 = *(const uint4*)(A + (size_t)(bm + r0) * 1024 + k0 + q0 * 8);
    uint4 va1 = *(const uint4*)(A + (size_t)(bm + r1) * 1024 + k0 + q1 * 8);
    uint4 vb0 = *(const uint4*)(Bm + (size_t)(bn + r0) * 1024 + k0 + q0 * 8);
    uint4 vb1 = *(const uint4*)(Bm + (size_t)(bn + r1) * 1024 + k0 + q1 * 8);
    *(uint4*)(As + r0 * LDA + q0 * 8) = va0;
    *(uint4*)(As + r1 * LDA + q1 * 8) = va1;
    *(uint4*)(Bs + r0 * LDA + q0 * 8) = vb0;
    *(uint4*)(Bs + r1 * LDA + q1 * 8) = vb1;
    __syncthreads();

    short8 afr[4], bfr[4];
    #pragma unroll
    for (int mt = 0; mt < 4; ++mt)
      afr[mt] = *(const short8*)(As + (wm + mt * 16 + lrow) * LDA + quad * 8);
    #pragma unroll
    for (int nt = 0; nt < 4; ++nt)
      bfr[nt] = *(const short8*)(Bs + (wn + nt * 16 + lrow) * LDA + quad * 8);
    #pragma unroll
    for (int mt = 0; mt < 4; ++mt)
      #pragma unroll
      for (int nt = 0; nt < 4; ++nt)
        acc[mt][nt] = __builtin_amdgcn_mfma_f32_16x16x32_bf16(
            afr[mt], bfr[nt], acc[mt][nt], 0, 0, 0);
  }

  #pragma unroll
  for (int nt = 0; nt < 4; ++nt) {
    int col = bn + wn + nt * 16 + lrow;
    float bv = bias[col];
    #pragma unroll
    for (int mt = 0; mt < 4; ++mt) {
      int row = bm + wm + mt * 16 + quad * 4;
      #pragma unroll
      for (int r = 0; r < 4; ++r)
        out[(size_t)(row + r) * VV + col] = acc[mt][nt][r] + bv;
    }
  }
}

// ---------------------------------------------------------------------------
extern "C" void kernel_launch(void* const* d_in, const int* in_sizes, int n_in,
                              void* d_out, int out_size, void* d_ws, size_t ws_size,
                              hipStream_t stream) {
  (void)in_sizes; (void)n_in; (void)out_size; (void)ws_size;
  const int*   seq  = (const int*)d_in[0];
  const float* emb  = (const float*)d_in[2];
  const float* fcb  = (const float*)d_in[3];
  const float* m1w  = (const float*)d_in[4];
  const float* m1b  = (const float*)d_in[5];
  const float* wih1 = (const float*)d_in[6];
  const float* whh1 = (const float*)d_in[7];
  const float* bih1 = (const float*)d_in[8];
  const float* bhh1 = (const float*)d_in[9];
  const float* m2w  = (const float*)d_in[10];
  const float* m2b  = (const float*)d_in[11];
  const float* wih2 = (const float*)d_in[12];
  const float* whh2 = (const float*)d_in[13];
  const float* bih2 = (const float*)d_in[14];
  const float* bhh2 = (const float*)d_in[15];

  // workspace layout (floats)
  float* w = (float*)d_ws;
  float* h1a = w;                 // 32768  (zeroed)
  float* h2a = w + 32768;         // 32768  (zeroed)
  float* c1  = w + 65536;         // 32768  (zeroed)
  float* c2  = w + 98304;         // 32768  (zeroed)
  float* h1b = w + 131072;
  float* h2b = w + 163840;
  float* x2  = w + 196608;
  float* xs  = w + 229376;        // T*B*H = 4194304 floats
  unsigned short* hidb = (unsigned short*)(w + 229376 + 4194304);   // B*T*H bf16
  unsigned short* embb = (unsigned short*)(w + 229376 + 4194304 + 2097152); // V*H bf16

  float* outp  = (float*)d_out;                          // [B,T,V]
  float* hid32 = outp + (size_t)BB * TT * VV;            // [B,T,H]

  // zero initial states (h1, h2, c1, c2 contiguous)
  hipMemsetAsync(h1a, 0, 4 * 32768 * sizeof(float), stream);

  gather_kernel<<<4096, 256, 0, stream>>>(seq, emb, xs);
  cvt_bf16_kernel<<<32000, 256, 0, stream>>>(emb, embb, VV * HH / 4);

  float* h1 = h1a; float* h1n = h1b;
  float* h2 = h2a; float* h2n = h2b;
  for (int t = 0; t < TT; ++t) {
    float* xt = xs + (size_t)t * BB * HH;
    // layer 1 mogrify (in-place on xt / h1 is safe: dots read the *other* vector)
    mog_kernel<<<256, 128, 0, stream>>>(h1, m1w + 0 * HSQ, m1b + 0 * HH, xt, xt);
    mog_kernel<<<256, 128, 0, stream>>>(xt, m1w + 1 * HSQ, m1b + 1 * HH, h1, h1);
    mog_kernel<<<256, 128, 0, stream>>>(h1, m1w + 2 * HSQ, m1b + 2 * HH, xt, xt);
    mog_kernel<<<256, 128, 0, stream>>>(xt, m1w + 3 * HSQ, m1b + 3 * HH, h1, h1);
    mog_kernel<<<256, 128, 0, stream>>>(h1, m1w + 4 * HSQ, m1b + 4 * HH, xt, xt);
    lstm_kernel<<<256, 256, 0, stream>>>(xt, h1, c1, wih1, whh1, bih1, bhh1,
                                         h1n, nullptr, nullptr, t);
    // layer 2 mogrify: x2 starts as a scaled copy of h1n (stage 0 writes x2)
    mog_kernel<<<256, 128, 0, stream>>>(h2, m2w + 0 * HSQ, m2b + 0 * HH, h1n, x2);
    mog_kernel<<<256, 128, 0, stream>>>(x2, m2w + 1 * HSQ, m2b + 1 * HH, h2, h2);
    mog_kernel<<<256, 128, 0, stream>>>(h2, m2w + 2 * HSQ, m2b + 2 * HH, x2, x2);
    mog_kernel<<<256, 128, 0, stream>>>(x2, m2w + 3 * HSQ, m2b + 3 * HH, h2, h2);
    mog_kernel<<<256, 128, 0, stream>>>(h2, m2w + 4 * HSQ, m2b + 4 * HH, x2, x2);
    lstm_kernel<<<256, 256, 0, stream>>>(x2, h2, c2, wih2, whh2, bih2, bhh2,
                                         h2n, hid32, hidb, t);
    // ping-pong recurrent state
    float* tmp;
    tmp = h1; h1 = h1n; h1n = tmp;
    tmp = h2; h2 = h2n; h2n = tmp;
  }

  gemm_kernel<<<dim3(250, 32), 256, 0, stream>>>(hidb, embb, fcb, outp);
}